// Round 6
// baseline (252.970 us; speedup 1.0000x reference)
//
#include <hip/hip_runtime.h>

typedef unsigned int u32;
typedef unsigned long long u64;
typedef float v2f __attribute__((ext_vector_type(2)));

#define NBATCH 8
#define NPTS   4096
#define NQTOT  (NBATCH * NPTS)   /* 32768 */
#define KNN    16
#define NBASIS 8
#define OUTM   64
#define NSPLIT 8
#define WIN    (NPTS / NSPLIT)   /* 512 candidates per window */
#define QPB    64
#define TKNN   (QPB * NSPLIT + 64) /* 8 scan waves + 1 digest wave = 576 */
#define GRP    8
/* Entry cap PER phase buffer. Concurrent digest means scan(ph) runs with
 * thr lagging one phase -> lambda <= 32 insertions/query/phase (was 16 with
 * synchronous digest). R4's failure was EXACTLY this: ECAP=64 at lambda=32
 * gives P(overflow) ~4e-6 per (query,phase) -> ~0.5 dropped-candidate events
 * per run -> absmax 6e-2. Cap 96: P(X>=96 | lam=32) = e^-41. */
#define ECAP   96
/* per-query LDS row (u64): 96 = two 96-entry u32 phase buffers (also seed
 * funnel [0,64) + epilogue float scratch [0,50)), + 16 t16 slots + 1 pad */
#define ROWSTR 113
#define TOFF   96

// sentinel: d2 = +inf, idx = all-ones (sorts last)
#define SENT 0x7f800000ffffffffull

__device__ __forceinline__ void ce(u64& x, u64& y) {
  u64 a = x, b = y;
  bool sw = b < a;
  x = sw ? b : a;
  y = sw ? a : b;
}

// Batcher odd-even mergesort network (fully unrolled).
template <int N>
__device__ __forceinline__ void oems_sort(u64* a) {
#pragma unroll
  for (int p = 1; p < N; p <<= 1) {
#pragma unroll
    for (int k = p; k >= 1; k >>= 1) {
#pragma unroll
      for (int j = k & (p - 1); j + k < N; j += 2 * k) {
#pragma unroll
        for (int i = 0; i < k; ++i) {
          int lo = i + j, hi = i + j + k;
          if (hi < N && (lo / (2 * p)) == (hi / (2 * p)))
            ce(a[lo], a[hi]);
        }
      }
    }
  }
}

// t, a sorted asc -> t = smallest 16 of union, sorted asc.
__device__ __forceinline__ void merge16(u64 t[16], const u64 a[16]) {
  u64 m[16];
#pragma unroll
  for (int i = 0; i < 16; ++i) {
    u64 x = t[i], y = a[15 - i];
    m[i] = (x < y) ? x : y;
  }
#pragma unroll
  for (int k = 8; k >= 1; k >>= 1) {
#pragma unroll
    for (int i = 0; i < 16; ++i) {
      if ((i & k) == 0) ce(m[i], m[i | k]);
    }
  }
#pragma unroll
  for (int i = 0; i < 16; ++i) t[i] = m[i];
}

// Bit-exact d2 pair: ((dx^2+dy^2)+dz^2), no FMA contraction. v_pk ops round
// IEEE-identically to scalar (verified bit-exact vs reference rounds 0-5).
__device__ __forceinline__ v2f d2pair(v2f cx, v2f cy, v2f cz, v2f qx, v2f qy,
                                      v2f qz) {
#pragma clang fp contract(off)
  v2f dx = cx - qx;
  v2f dy = cy - qy;
  v2f dz = cz - qz;
  v2f d2 = (dx * dx + dy * dy) + dz * dz;
  return d2;
}

// Scalar bit-exact d2 (identical rounding to d2pair) — digest recompute.
// Proven bit-exact vs reference in rounds 1 and 5.
__device__ __forceinline__ float d2s(float cx, float cy, float cz, float qx,
                                     float qy, float qz) {
#pragma clang fp contract(off)
  float dx = cx - qx;
  float dy = cy - qy;
  float dz = cz - qz;
  return (dx * dx + dy * dy) + dz * dz;
}

// Fused kNN + tensor-product features — pipelined producer/consumer.
// 8 scan waves (one 512-candidate window each) + 1 DEDICATED digest wave.
// Scan stores ONE u32 group-entry (want<<12 | candbase) per hit-group (R5,
// proven). Digest wave expands phase ph-1's entries (decode -> gather cpad
// -> bit-exact scalar d2 recompute -> sort/merge into running top-16)
// CONCURRENTLY with scan of phase ph, via double-buffered 96-entry lists.
// One barrier per phase. Scanners re-read thr per group (volatile; stale
// thr is an upper bound on the true 16th distance -> admission superset ->
// selection bit-identical; extras discarded by exact-key merge). ECAP=96
// absorbs the stale-thr insertion rate (lambda<=32; R4's ECAP=64 overflowed
// and corrupted results). NO __launch_bounds__ min-waves (forced VGPR ->
// scratch spills, measured rounds 7/8 of prior session).
__global__ __launch_bounds__(TKNN) void se3_kernel(
    const float* __restrict__ Xp, const float* __restrict__ Yp,
    const float* __restrict__ Zp, const float4* __restrict__ cpad,
    const float* __restrict__ Wmat, float* __restrict__ out) {
  __shared__ u64 sBuf[QPB * ROWSTR];  // 57.9 KB
  __shared__ u32 sCnt[2 * QPB];       // per-phase-buffer insertion counts
  __shared__ float sThr[QPB];
  __shared__ float sM[QPB * 25];      // reduced M[8][3], stride 25

  const int b = blockIdx.x;
  const int qg = blockIdx.y;
  const int tid = threadIdx.x;
  const int ql = tid & 63;
  const int sp = tid >> 6;  // 0..7 scan windows, 8 = digest wave
  const int qi = qg * QPB + ql;
  const int base = b * NPTS;

  if (tid < 2 * QPB) sCnt[tid] = 0;

  // per-lane query coords (all waves incl. digest — it recomputes d2)
  const float qx = Xp[base + qi];
  const float qy = Yp[base + qi];
  const float qz = Zp[base + qi];
  const v2f qxx = {qx, qx}, qyy = {qy, qy}, qzz = {qz, qz};

  // wave-uniform candidate window -> scalar loads feeding packed math
  // (sp==8: pointers computed but never dereferenced)
  const int wbase = __builtin_amdgcn_readfirstlane((sp & 7) * WIN);
  const v2f* xs2 = (const v2f*)(Xp + base + wbase);
  const v2f* ys2 = (const v2f*)(Yp + base + wbase);
  const v2f* zs2 = (const v2f*)(Zp + base + wbase);
  const int sj = qi - wbase;  // self position inside window (may be OOR)

  u64* row = sBuf + (size_t)ql * ROWSTR;

  // ---- Seed: scan waves sort their window's first 16; 2-round funnel ----
  {
    u64 s16[16];
    if (sp < 8) {
      float cd[16];
#pragma unroll
      for (int p = 0; p < 8; ++p) {
        v2f d2 = d2pair(xs2[p], ys2[p], zs2[p], qxx, qyy, qzz);
        cd[2 * p + 0] = d2.x;
        cd[2 * p + 1] = d2.y;
      }
#pragma unroll
      for (int i = 0; i < 16; ++i) {
        u64 v = ((u64)__float_as_uint(cd[i]) << 32) | (u32)(wbase + i);
        s16[i] = (i == sj) ? SENT : v;
      }
      oems_sort<16>(s16);
    }

    // Round A: waves 1..4 publish pre-sorted lists into funnel slots.
    if (sp >= 1 && sp <= 4) {
#pragma unroll
      for (int e = 0; e < 16; ++e) row[(sp - 1) * 16 + e] = s16[e];
    }
    __syncthreads();
    if (sp == 0) {
      u64 t16[16];
#pragma unroll
      for (int e = 0; e < 16; ++e) t16[e] = s16[e];
#pragma unroll
      for (int s = 0; s < 4; ++s) {
        u64 a[16];
#pragma unroll
        for (int e = 0; e < 16; ++e) a[e] = row[s * 16 + e];
        merge16(t16, a);
      }
      // stash partial in t16 region while round B publishes
#pragma unroll
      for (int e = 0; e < 16; ++e) row[TOFF + e] = t16[e];
    }
    __syncthreads();
    // Round B: waves 5..7 publish.
    if (sp >= 5 && sp < 8) {
#pragma unroll
      for (int e = 0; e < 16; ++e) row[(sp - 5) * 16 + e] = s16[e];
    }
    __syncthreads();
    if (sp == 0) {
      u64 t16[16];
#pragma unroll
      for (int e = 0; e < 16; ++e) t16[e] = row[TOFF + e];
#pragma unroll
      for (int s = 0; s < 3; ++s) {
        u64 a[16];
#pragma unroll
        for (int e = 0; e < 16; ++e) a[e] = row[s * 16 + e];
        merge16(t16, a);
      }
#pragma unroll
      for (int e = 0; e < 16; ++e) row[TOFF + e] = t16[e];
      sThr[ql] = __uint_as_float((u32)(t16[15] >> 32));
    }
    __syncthreads();
  }

  // self-exclusion mask precompute (garbage for sp==8, unused there)
  const int selfgrp = (sj >= 0 && sj < WIN) ? (sj >> 3) : -1;
  const u32 selfbit = 1u << (sj & 7);

  volatile float* vThr = sThr;  // digest tightens mid-phase; re-read per group

  // ---- Pipelined phases: scan(ph) || digest(ph-1); 1 barrier/phase ----
#pragma unroll
  for (int ph = 0; ph <= 5; ++ph) {
    if (sp < 8 && ph < 5) {
      // ---- scan phase ph: candidates [16<<ph, 32<<ph) of this window ----
      const int cb = ph & 1;
      u32* ebuf = (u32*)row + cb * ECAP;
      u32* cnt = &sCnt[cb * QPB + ql];
      const int cstart = 16 << ph;
      const int cend = 32 << ph;
#pragma unroll 2
      for (int g = cstart; g < cend; g += GRP) {
        v2f d2p[4];
#pragma unroll
        for (int p = 0; p < 4; ++p)
          d2p[p] = d2pair(xs2[(g >> 1) + p], ys2[(g >> 1) + p],
                          zs2[(g >> 1) + p], qxx, qyy, qzz);
        float thr = vThr[ql];
        u32 want = 0;
#pragma unroll
        for (int i = 0; i < GRP; ++i)
          want |= (d2p[i >> 1][i & 1] <= thr) ? (1u << i) : 0u;
        if ((g >> 3) == selfgrp) want &= ~selfbit;
        if (want) {  // ONE u32 entry per group with any hit
          u32 slot = atomicAdd(cnt, 1u);
          if (slot < ECAP) ebuf[slot] = (want << 12) | (u32)(wbase + g);
        }
      }
    } else if (sp == 8 && ph >= 1) {
      // ---- digest phase ph-1's buffer (concurrent with scan of ph) ----
      const int pb = (ph - 1) & 1;
      const u32* ebuf = (const u32*)row + pb * ECAP;
      int n = (int)sCnt[pb * QPB + ql];
      n = n < ECAP ? n : ECAP;
      u64 t16[16];
#pragma unroll
      for (int e = 0; e < 16; ++e) t16[e] = row[TOFF + e];
      int cursor = 0;
      u32 curWant = 0, curBase = 0;
      while (__any(cursor < n || curWant != 0)) {
        // pass 1: decode up to 16 candidate indices (VALU only)
        u32 kidx[16];
        u32 vmask = 0;
#pragma unroll
        for (int e = 0; e < 16; ++e) {
          if (curWant == 0 && cursor < n) {
            u32 ent = ebuf[cursor++];
            curWant = ent >> 12;
            curBase = ent & 0xFFFu;
          }
          if (curWant) {
            int bit = __ffs(curWant) - 1;
            curWant &= curWant - 1;
            kidx[e] = curBase + (u32)bit;
            vmask |= (1u << e);
          } else {
            kidx[e] = 0;
          }
        }
        // pass 2: batched gathers + bit-exact d2 recompute
        u64 a[16];
#pragma unroll
        for (int e = 0; e < 16; ++e) {
          float4 c = cpad[base + (int)kidx[e]];
          float d2 = d2s(c.x, c.y, c.z, qx, qy, qz);
          u64 key = ((u64)__float_as_uint(d2) << 32) | kidx[e];
          a[e] = (vmask & (1u << e)) ? key : SENT;
        }
        oems_sort<16>(a);
        merge16(t16, a);
      }
#pragma unroll
      for (int e = 0; e < 16; ++e) row[TOFF + e] = t16[e];
      sThr[ql] = __uint_as_float((u32)(t16[15] >> 32));
      sCnt[pb * QPB + ql] = 0;
    }
    __syncthreads();
  }

  // ---- Epilogue phase 1 (waves 0-3): partial M over 4 neighbors each ----
  // Partials into dead entry-buffer floats [k*25, k*25+24) of row q
  // (< float offset 100; t16 region starts at float offset 192).
  if (sp < 4) {
    const int k = sp;
    u64 pv[4];
#pragma unroll
    for (int e = 0; e < 4; ++e) pv[e] = row[TOFF + k * 4 + e];
    float4 nc[4];
    float dd[4];
#pragma unroll
    for (int e = 0; e < 4; ++e) {
      nc[e] = cpad[base + (int)(u32)pv[e]];  // independent gathers
      dd[e] = __uint_as_float((u32)(pv[e] >> 32));
    }
    float M[24];
#pragma unroll
    for (int j = 0; j < 24; ++j) M[j] = 0.f;
#pragma unroll
    for (int e = 0; e < 4; ++e) {
      float rx = nc[e].x - qx;  // sender - receiver
      float ry = nc[e].y - qy;
      float rz = nc[e].z - qz;
      float dist = sqrtf(dd[e]);
      float inv = 1.0f / (dist + 1e-8f);
      rx *= inv; ry *= inv; rz *= inv;
      float cut = fminf(dist * 0.1f, 1.0f);
      float g[NBASIS], s = 0.f;
#pragma unroll
      for (int v = 0; v < NBASIS; ++v) {
        float t = cut - (float)v * (1.0f / 7.0f);
        g[v] = __expf(-32.0f * t * t);  // sigma = 1/8 -> 1/(2s^2) = 32
        s += g[v];
      }
      float rs = 1.0f / s;
#pragma unroll
      for (int v = 0; v < NBASIS; ++v) {
        float rb = g[v] * rs;
        M[v * 3 + 0] = fmaf(rb, rx, M[v * 3 + 0]);
        M[v * 3 + 1] = fmaf(rb, ry, M[v * 3 + 1]);
        M[v * 3 + 2] = fmaf(rb, rz, M[v * 3 + 2]);
      }
    }
    float* fp = (float*)row;
#pragma unroll
    for (int c = 0; c < 24; ++c) fp[k * 25 + c] = M[c];
  }
  __syncthreads();

  // ---- Reduce partials: thread (q = ql, comps sp*3..sp*3+2), sp<8 ----
  if (sp < 8) {
    const float* fp = (const float*)row;
#pragma unroll
    for (int j0 = 0; j0 < 3; ++j0) {
      int j = sp * 3 + j0;
      float s = fp[0 * 25 + j] + fp[1 * 25 + j] + fp[2 * 25 + j] +
                fp[3 * 25 + j];
      sM[ql * 25 + j] = s;
    }
  }
  __syncthreads();

  // ---- Epilogue phase 2 (scan waves): out[q][w*3+m], lane w = ql ----
  if (sp < 8) {
    float wreg[NBASIS];
#pragma unroll
    for (int v = 0; v < NBASIS; ++v) wreg[v] = Wmat[v * OUTM + ql];
    const float scale = 0.022097086912079608f;  // (1/sqrt(8)) / 16
#pragma unroll
    for (int i = 0; i < 8; ++i) {
      int q = sp * 8 + i;  // wave-uniform -> sM broadcasts
      const float* mq = sM + q * 25;
      float a0 = 0.f, a1 = 0.f, a2 = 0.f;
#pragma unroll
      for (int v = 0; v < NBASIS; ++v) {
        a0 = fmaf(wreg[v], mq[v * 3 + 0], a0);
        a1 = fmaf(wreg[v], mq[v * 3 + 1], a1);
        a2 = fmaf(wreg[v], mq[v * 3 + 2], a2);
      }
      size_t o = (size_t)(base + qg * QPB + q) * (OUTM * 3) + ql * 3;
      out[o + 0] = a0 * scale;
      out[o + 1] = a1 * scale;
      out[o + 2] = a2 * scale;
    }
  }
}

// coords [B*N][3] -> x/y/z planes + float4 array.
__global__ void prep_kernel(const float* __restrict__ coords,
                            float* __restrict__ Xp, float* __restrict__ Yp,
                            float* __restrict__ Zp, float4* __restrict__ cpad) {
  int i = blockIdx.x * 256 + threadIdx.x;
  if (i < NQTOT) {
    float x = coords[3 * i + 0];
    float y = coords[3 * i + 1];
    float z = coords[3 * i + 2];
    Xp[i] = x; Yp[i] = y; Zp[i] = z;
    cpad[i] = make_float4(x, y, z, 0.f);
  }
}

extern "C" void kernel_launch(void* const* d_in, const int* in_sizes, int n_in,
                              void* d_out, int out_size, void* d_ws, size_t ws_size,
                              hipStream_t stream) {
  const float* coords = (const float*)d_in[0];
  const float* Wmat = (const float*)d_in[1];
  float* out = (float*)d_out;

  char* w = (char*)d_ws;
  float* Xp = (float*)(w);               // 128 KB
  float* Yp = (float*)(w + 131072);
  float* Zp = (float*)(w + 262144);
  float4* cpad = (float4*)(w + 393216);  // 512 KB

  prep_kernel<<<dim3((NQTOT + 255) / 256), dim3(256), 0, stream>>>(coords, Xp, Yp, Zp, cpad);
  se3_kernel<<<dim3(NBATCH, NPTS / QPB), dim3(TKNN), 0, stream>>>(Xp, Yp, Zp, cpad, Wmat, out);
}

// Round 7
// 168.723 us; speedup vs baseline: 1.4993x; 1.4993x over previous
//
#include <hip/hip_runtime.h>

typedef unsigned int u32;
typedef unsigned long long u64;
typedef float v2f __attribute__((ext_vector_type(2)));

#define NBATCH 8
#define NPTS   4096
#define NQTOT  (NBATCH * NPTS)   /* 32768 */
#define KNN    16
#define NBASIS 8
#define OUTM   64
#define NSPLIT 8
#define WIN    (NPTS / NSPLIT)   /* 512 candidates per window */
#define QPB    64
#define TKNN   (QPB * NSPLIT)    /* 512 threads = 8 waves */
#define GRP    8
#define ECAP   64                /* synchronous digest: thr never stale ->
                                  * lambda ~16/phase, cap 64 proven (R3/R5) */
/* per-query LDS row (u64): [0,32) = 2 seed-funnel segments / 64-u32 entry
 * buffer / epilogue scratch; [32,48) = t16 (also 3rd funnel seg during seed,
 * before t16 exists; clobbered by epilogue scratch after pv read); [48] pad.
 * Row = 49 u64 = 392 B -> block LDS ~32 KB -> 3 blocks/CU (R5 proved the
 * pool holds >= 97.3 KB; R6's 63.5 KB block dropped to 1 block/CU = +74%). */
#define ROWSTR 49
#define TOFF   32

// sentinel: d2 = +inf, idx = all-ones (sorts last)
#define SENT 0x7f800000ffffffffull

__device__ __forceinline__ void ce(u64& x, u64& y) {
  u64 a = x, b = y;
  bool sw = b < a;
  x = sw ? b : a;
  y = sw ? a : b;
}

// Batcher odd-even mergesort network (fully unrolled).
template <int N>
__device__ __forceinline__ void oems_sort(u64* a) {
#pragma unroll
  for (int p = 1; p < N; p <<= 1) {
#pragma unroll
    for (int k = p; k >= 1; k >>= 1) {
#pragma unroll
      for (int j = k & (p - 1); j + k < N; j += 2 * k) {
#pragma unroll
        for (int i = 0; i < k; ++i) {
          int lo = i + j, hi = i + j + k;
          if (hi < N && (lo / (2 * p)) == (hi / (2 * p)))
            ce(a[lo], a[hi]);
        }
      }
    }
  }
}

// t, a sorted asc -> t = smallest 16 of union, sorted asc.
__device__ __forceinline__ void merge16(u64 t[16], const u64 a[16]) {
  u64 m[16];
#pragma unroll
  for (int i = 0; i < 16; ++i) {
    u64 x = t[i], y = a[15 - i];
    m[i] = (x < y) ? x : y;
  }
#pragma unroll
  for (int k = 8; k >= 1; k >>= 1) {
#pragma unroll
    for (int i = 0; i < 16; ++i) {
      if ((i & k) == 0) ce(m[i], m[i | k]);
    }
  }
#pragma unroll
  for (int i = 0; i < 16; ++i) t[i] = m[i];
}

// Bit-exact d2 pair: ((dx^2+dy^2)+dz^2), no FMA contraction. v_pk ops round
// IEEE-identically to scalar (verified bit-exact vs reference rounds 0-6).
__device__ __forceinline__ v2f d2pair(v2f cx, v2f cy, v2f cz, v2f qx, v2f qy,
                                      v2f qz) {
#pragma clang fp contract(off)
  v2f dx = cx - qx;
  v2f dy = cy - qy;
  v2f dz = cz - qz;
  v2f d2 = (dx * dx + dy * dy) + dz * dz;
  return d2;
}

// Scalar bit-exact d2 (identical rounding to d2pair) — digest recompute.
// Proven bit-exact vs reference in rounds 1, 5, 6.
__device__ __forceinline__ float d2s(float cx, float cy, float cz, float qx,
                                     float qy, float qz) {
#pragma clang fp contract(off)
  float dx = cx - qx;
  float dy = cy - qy;
  float dz = cz - qz;
  return (dx * dx + dy * dy) + dz * dz;
}

// publish a sorted 16-list into funnel segment seg of this query's row
__device__ __forceinline__ void pub16(u64* row, int seg, const u64 s[16]) {
#pragma unroll
  for (int e = 0; e < 16; ++e) row[seg * 16 + e] = s[e];
}

// merge funnel segment seg into register list s
__device__ __forceinline__ void mrg16(const u64* row, int seg, u64 s[16]) {
  u64 a[16];
#pragma unroll
  for (int e = 0; e < 16; ++e) a[e] = row[seg * 16 + e];
  merge16(s, a);
}

// Fused kNN + tensor-product features — R5 compute structure (synchronous
// rotating digest + group-encoded entries, both proven) at 32 KB LDS/block
// for 3-blocks/CU residency. Seed merges via a 3-segment tree (segments 0,1
// + the t16 region, free during seed); epilogue scratch reuses the whole
// row after pv is read (one extra barrier orders read-before-clobber).
// NO __launch_bounds__ min-waves (forced VGPR -> scratch spills, measured).
__global__ __launch_bounds__(TKNN) void se3_kernel(
    const float* __restrict__ Xp, const float* __restrict__ Yp,
    const float* __restrict__ Zp, const float4* __restrict__ cpad,
    const float* __restrict__ Wmat, float* __restrict__ out) {
  __shared__ u64 sBuf[QPB * ROWSTR];  // 25.1 KB
  __shared__ u32 sCnt[QPB];
  __shared__ float sThr[QPB];
  __shared__ float sM[QPB * 25];      // reduced M[8][3], stride 25

  const int b = blockIdx.x;
  const int qg = blockIdx.y;
  const int tid = threadIdx.x;
  const int ql = tid & 63;
  const int sp = tid >> 6;  // window id, wave-uniform
  const int qi = qg * QPB + ql;
  const int base = b * NPTS;

  if (tid < QPB) sCnt[tid] = 0;

  // per-lane query coords (coalesced)
  const float qx = Xp[base + qi];
  const float qy = Yp[base + qi];
  const float qz = Zp[base + qi];
  const v2f qxx = {qx, qx}, qyy = {qy, qy}, qzz = {qz, qz};

  // wave-uniform candidate window -> scalar loads feeding packed math
  const int wbase = __builtin_amdgcn_readfirstlane(sp * WIN);
  const v2f* xs2 = (const v2f*)(Xp + base + wbase);
  const v2f* ys2 = (const v2f*)(Yp + base + wbase);
  const v2f* zs2 = (const v2f*)(Zp + base + wbase);
  const int sj = qi - wbase;  // self position inside window (may be OOR)

  u64* row = sBuf + (size_t)ql * ROWSTR;

  // ---- Seed: every wave sorts its window's first 16; 3-seg tree merge ----
  {
    u64 s16[16];
    float cd[16];
#pragma unroll
    for (int p = 0; p < 8; ++p) {
      v2f d2 = d2pair(xs2[p], ys2[p], zs2[p], qxx, qyy, qzz);
      cd[2 * p + 0] = d2.x;
      cd[2 * p + 1] = d2.y;
    }
#pragma unroll
    for (int i = 0; i < 16; ++i) {
      u64 v = ((u64)__float_as_uint(cd[i]) << 32) | (u32)(wbase + i);
      s16[i] = (i == sj) ? SENT : v;
    }
    oems_sort<16>(s16);

    // P1: w5,w6,w7 -> segs 0,1,2 (seg2 = t16 region, free during seed)
    if (sp >= 5) pub16(row, sp - 5, s16);
    __syncthreads();
    if (sp >= 1 && sp <= 3) mrg16(row, sp - 1, s16);  // {1,5} {2,6} {3,7}
    __syncthreads();
    // P2: w4 -> seg0, w3 -> seg1
    if (sp == 4) pub16(row, 0, s16);
    if (sp == 3) pub16(row, 1, s16);
    __syncthreads();
    if (sp == 0) mrg16(row, 0, s16);  // {0,4}
    if (sp == 1) mrg16(row, 1, s16);  // {1,5,3,7}
    __syncthreads();
    // P3: w2 -> seg0, w1 -> seg1
    if (sp == 2) pub16(row, 0, s16);
    if (sp == 1) pub16(row, 1, s16);
    __syncthreads();
    if (sp == 0) {
      mrg16(row, 0, s16);  // {0,4,2,6}
      mrg16(row, 1, s16);  // all 8 windows
#pragma unroll
      for (int e = 0; e < 16; ++e) row[TOFF + e] = s16[e];
      sThr[ql] = __uint_as_float((u32)(s16[15] >> 32));
    }
    __syncthreads();
  }
  float thr = sThr[ql];

  // self-exclusion mask precompute (avoids per-candidate j!=qi compare)
  const int selfgrp = (sj >= 0 && sj < WIN) ? (sj >> 3) : -1;
  const u32 selfbit = 1u << (sj & 7);

  // entry buffer: u32 slots [0,64) of the row = u64 slots [0,32)
  u32* ebuf = (u32*)row;

  // ---- Main scan: doubling phases; digest wave rotates (1..5) ----
#pragma unroll
  for (int ph = 0; ph < 5; ++ph) {
    const int cstart = 16 << ph;  // [16,32),[32,64),...,[256,512)
    const int cend = 32 << ph;
#pragma unroll 2
    for (int g = cstart; g < cend; g += GRP) {
      v2f d2p[4];
#pragma unroll
      for (int p = 0; p < 4; ++p)
        d2p[p] = d2pair(xs2[(g >> 1) + p], ys2[(g >> 1) + p],
                        zs2[(g >> 1) + p], qxx, qyy, qzz);
      u32 want = 0;
#pragma unroll
      for (int i = 0; i < GRP; ++i)
        want |= (d2p[i >> 1][i & 1] <= thr) ? (1u << i) : 0u;
      if ((g >> 3) == selfgrp) want &= ~selfbit;
      if (want) {  // ONE u32 entry per group with any hit
        u32 slot = atomicAdd(&sCnt[ql], 1u);
        if (slot < ECAP) ebuf[slot] = (want << 12) | (u32)(wbase + g);
      }
    }
    __syncthreads();
    if (sp == ph + 1) {  // rotating digest wave (1..5), between barriers
      int n = (int)sCnt[ql];
      n = n < ECAP ? n : ECAP;
      if (__any(n > 0)) {
        u64 t16[16];
#pragma unroll
        for (int e = 0; e < 16; ++e) t16[e] = row[TOFF + e];
        int cursor = 0;
        u32 curWant = 0, curBase = 0;
        while (__any(cursor < n || curWant != 0)) {
          // pass 1: decode up to 16 candidate indices (VALU only)
          u32 kidx[16];
          u32 vmask = 0;
#pragma unroll
          for (int e = 0; e < 16; ++e) {
            if (curWant == 0 && cursor < n) {
              u32 ent = ebuf[cursor++];
              curWant = ent >> 12;
              curBase = ent & 0xFFFu;
            }
            if (curWant) {
              int bit = __ffs(curWant) - 1;
              curWant &= curWant - 1;
              kidx[e] = curBase + (u32)bit;
              vmask |= (1u << e);
            } else {
              kidx[e] = 0;
            }
          }
          // pass 2: batched gathers + bit-exact d2 recompute
          u64 a[16];
#pragma unroll
          for (int e = 0; e < 16; ++e) {
            float4 c = cpad[base + (int)kidx[e]];
            float d2 = d2s(c.x, c.y, c.z, qx, qy, qz);
            u64 key = ((u64)__float_as_uint(d2) << 32) | kidx[e];
            a[e] = (vmask & (1u << e)) ? key : SENT;
          }
          oems_sort<16>(a);
          merge16(t16, a);
        }
#pragma unroll
        for (int e = 0; e < 16; ++e) row[TOFF + e] = t16[e];
        sThr[ql] = __uint_as_float((u32)(t16[15] >> 32));
      }
      sCnt[ql] = 0;
    }
    __syncthreads();
    thr = sThr[ql];
  }

  // ---- Epilogue phase 1 (waves 0-3): partial M over 4 neighbors each ----
  // pv is read by ALL participating threads first; the barrier then orders
  // those reads before scratch writes clobber the t16 region (row floats
  // [0,96) = the whole row incl. t16 floats [64,96), all dead afterward).
  u64 pv[4];
  if (sp < 4) {
#pragma unroll
    for (int e = 0; e < 4; ++e) pv[e] = row[TOFF + sp * 4 + e];
  }
  __syncthreads();
  if (sp < 4) {
    const int k = sp;
    float4 nc[4];
    float dd[4];
#pragma unroll
    for (int e = 0; e < 4; ++e) {
      nc[e] = cpad[base + (int)(u32)pv[e]];  // independent gathers
      dd[e] = __uint_as_float((u32)(pv[e] >> 32));
    }
    float M[24];
#pragma unroll
    for (int j = 0; j < 24; ++j) M[j] = 0.f;
#pragma unroll
    for (int e = 0; e < 4; ++e) {
      float rx = nc[e].x - qx;  // sender - receiver
      float ry = nc[e].y - qy;
      float rz = nc[e].z - qz;
      float dist = sqrtf(dd[e]);
      float inv = 1.0f / (dist + 1e-8f);
      rx *= inv; ry *= inv; rz *= inv;
      float cut = fminf(dist * 0.1f, 1.0f);
      float g[NBASIS], s = 0.f;
#pragma unroll
      for (int v = 0; v < NBASIS; ++v) {
        float t = cut - (float)v * (1.0f / 7.0f);
        g[v] = __expf(-32.0f * t * t);  // sigma = 1/8 -> 1/(2s^2) = 32
        s += g[v];
      }
      float rs = 1.0f / s;
#pragma unroll
      for (int v = 0; v < NBASIS; ++v) {
        float rb = g[v] * rs;
        M[v * 3 + 0] = fmaf(rb, rx, M[v * 3 + 0]);
        M[v * 3 + 1] = fmaf(rb, ry, M[v * 3 + 1]);
        M[v * 3 + 2] = fmaf(rb, rz, M[v * 3 + 2]);
      }
    }
    float* fp = (float*)row;
#pragma unroll
    for (int c = 0; c < 24; ++c) fp[k * 24 + c] = M[c];  // floats [0,96)
  }
  __syncthreads();

  // ---- Reduce partials: thread (q = ql, comps sp*3..sp*3+2) ----
  {
    const float* fp = (const float*)row;
#pragma unroll
    for (int j0 = 0; j0 < 3; ++j0) {
      int j = sp * 3 + j0;
      float s = fp[0 * 24 + j] + fp[1 * 24 + j] + fp[2 * 24 + j] +
                fp[3 * 24 + j];
      sM[ql * 25 + j] = s;
    }
  }
  __syncthreads();

  // ---- Epilogue phase 2 (all waves): out[q][w*3+m], lane w = ql ----
  float wreg[NBASIS];
#pragma unroll
  for (int v = 0; v < NBASIS; ++v) wreg[v] = Wmat[v * OUTM + ql];
  const float scale = 0.022097086912079608f;  // (1/sqrt(8)) / 16
#pragma unroll
  for (int i = 0; i < 8; ++i) {
    int q = sp * 8 + i;  // wave-uniform -> sM broadcasts
    const float* mq = sM + q * 25;
    float a0 = 0.f, a1 = 0.f, a2 = 0.f;
#pragma unroll
    for (int v = 0; v < NBASIS; ++v) {
      a0 = fmaf(wreg[v], mq[v * 3 + 0], a0);
      a1 = fmaf(wreg[v], mq[v * 3 + 1], a1);
      a2 = fmaf(wreg[v], mq[v * 3 + 2], a2);
    }
    size_t o = (size_t)(base + qg * QPB + q) * (OUTM * 3) + ql * 3;
    out[o + 0] = a0 * scale;
    out[o + 1] = a1 * scale;
    out[o + 2] = a2 * scale;
  }
}

// coords [B*N][3] -> x/y/z planes + float4 array.
__global__ void prep_kernel(const float* __restrict__ coords,
                            float* __restrict__ Xp, float* __restrict__ Yp,
                            float* __restrict__ Zp, float4* __restrict__ cpad) {
  int i = blockIdx.x * 256 + threadIdx.x;
  if (i < NQTOT) {
    float x = coords[3 * i + 0];
    float y = coords[3 * i + 1];
    float z = coords[3 * i + 2];
    Xp[i] = x; Yp[i] = y; Zp[i] = z;
    cpad[i] = make_float4(x, y, z, 0.f);
  }
}

extern "C" void kernel_launch(void* const* d_in, const int* in_sizes, int n_in,
                              void* d_out, int out_size, void* d_ws, size_t ws_size,
                              hipStream_t stream) {
  const float* coords = (const float*)d_in[0];
  const float* Wmat = (const float*)d_in[1];
  float* out = (float*)d_out;

  char* w = (char*)d_ws;
  float* Xp = (float*)(w);               // 128 KB
  float* Yp = (float*)(w + 131072);
  float* Zp = (float*)(w + 262144);
  float4* cpad = (float4*)(w + 393216);  // 512 KB

  prep_kernel<<<dim3((NQTOT + 255) / 256), dim3(256), 0, stream>>>(coords, Xp, Yp, Zp, cpad);
  se3_kernel<<<dim3(NBATCH, NPTS / QPB), dim3(TKNN), 0, stream>>>(Xp, Yp, Zp, cpad, Wmat, out);
}